// Round 11
// baseline (35.658 us; speedup 1.0000x reference)
//
#include <hip/hip_runtime.h>
#include <hip/hip_bf16.h>
#include <stdint.h>

// LogLinearCDE: out = softmax(W_out @ (y0 * prod_l flows[l]) + b_out)
// flows[l,h] = 1 + sum_c logsigs[l,c]*vf_A[c,h];  y0 = W_in@x0 + b_in
// R11: R9 skeleton (4 kernels, no fences) + 2-MFMA 51-dim concat packing:
// S = Ah.Bh + Ah.Bl + Al.Bh  ==  contraction over 51 concat dims
//   frag1 (t=0..31):  a=[Ah(0..16),Ah(0..14)]  b=[Bh(0..16),Bl(0..14)]
//   frag2 (t=32..50): a=[Ah(15,16),Al(0..16)]  b=[Bl(15,16),Bh(0..16)]
// -> 2 MFMAs per 16x16 tile instead of 3 (-33% matrix-pipe time).

#define LSTEPS 16384
#define HID    4096
#define CC     17
#define NLAB   10
#define NCHUNK 256
#define CR     64          // rows per chunk
#define APAD   20          // LDS A row stride in words (80B, 16B-aligned)
#define HPB    16          // h per tailA block
#define RBLK   256         // tailA blocks

typedef __attribute__((ext_vector_type(8))) short short8;
typedef __attribute__((ext_vector_type(4))) float f32x4;

static __device__ __forceinline__ unsigned short f2bf(float x) {
  __hip_bfloat16 h = __float2bfloat16(x);
  return *reinterpret_cast<unsigned short*>(&h);
}
static __device__ __forceinline__ float bf2f(unsigned short u) {
  __hip_bfloat16 h; *reinterpret_cast<unsigned short*>(&h) = u;
  return __bfloat162float(h);
}

// concat-dim helpers (t in [0,64)), resolved at compile time under unroll
static __device__ __forceinline__ unsigned short a_slot(const float* v, int t) {
  // v = row of CC fp32
  if (t < 17)      return f2bf(v[t]);                      // Ah
  else if (t < 34) return f2bf(v[t-17]);                   // Ah
  else if (t < 51) { float x = v[t-34]; return f2bf(x - bf2f(f2bf(x))); } // Al
  return 0;
}
static __device__ __forceinline__ unsigned short b_slot(const unsigned short* bh,
                                                        const unsigned short* bl, int t) {
  if (t < 17)      return bh[t];
  else if (t < 34) return bl[t-17];
  else if (t < 51) return bh[t-34];
  return 0;
}

// pre-pass: pack vf_A column c into 2 concat fragments (32 u32 words).
__global__ __launch_bounds__(256) void pack_vfA_kernel(
    const float* __restrict__ vfA, uint32_t* __restrict__ pB) {
  const int c = blockIdx.x*256 + threadIdx.x;
  unsigned short bh[CC], bl[CC];
  #pragma unroll
  for (int k = 0; k < CC; ++k) {
    const float v = vfA[(size_t)k*HID + c];
    bh[k] = f2bf(v);
    bl[k] = f2bf(v - bf2f(bh[k]));
  }
  #pragma unroll
  for (int j = 0; j < 16; ++j) {   // frag1 words
    pB[(size_t)c*32 + j] =
        (uint32_t)b_slot(bh, bl, 2*j) | ((uint32_t)b_slot(bh, bl, 2*j+1) << 16);
  }
  #pragma unroll
  for (int j = 0; j < 16; ++j) {   // frag2 words
    pB[(size_t)c*32 + 16 + j] =
        (uint32_t)b_slot(bh, bl, 32+2*j) | ((uint32_t)b_slot(bh, bl, 32+2*j+1) << 16);
  }
}

// partial products over 64-row chunks via MFMA (2 MFMAs per 16x16 tile)
__global__ __launch_bounds__(256, 4) void partial_mfma_kernel(
    const float* __restrict__ logsigs, const uint32_t* __restrict__ pB,
    float* __restrict__ ws_p) {
  const int hb = blockIdx.x;        // 0..3 (1024 cols each)
  const int chunk = blockIdx.y;     // 0..255
  const int tid = threadIdx.x;

  __shared__ __align__(16) uint32_t sA1[CR][APAD], sA2[CR][APAD];

  // stage: thread e -> (row r, word j); build both fragments' word j
  const float* __restrict__ src = logsigs + (size_t)chunk*CR*CC;
  for (int e = tid; e < CR*16; e += 256) {
    const int r = e >> 4, j = e & 15;
    const float* row = src + r*CC;
    sA1[r][j] = (uint32_t)a_slot(row, 2*j) | ((uint32_t)a_slot(row, 2*j+1) << 16);
    sA2[r][j] = (uint32_t)a_slot(row, 32+2*j) | ((uint32_t)a_slot(row, 32+2*j+1) << 16);
  }
  __syncthreads();

  const int wv = tid >> 6, lane = tid & 63;
  const int g = lane >> 4, cr = lane & 15;

  short8 A1[4], A2[4];
  #pragma unroll
  for (int mt = 0; mt < 4; ++mt) {
    const int r = mt*16 + cr;
    A1[mt] = *reinterpret_cast<const short8*>(&sA1[r][4*g]);
    A2[mt] = *reinterpret_cast<const short8*>(&sA2[r][4*g]);
  }

  const int cbase = hb*1024 + wv*256;
  #pragma unroll 2
  for (int nt = 0; nt < 16; ++nt) {
    const int c = cbase + nt*16 + cr;
    const short8 B1 = *reinterpret_cast<const short8*>(&pB[(size_t)c*32 + 4*g]);
    const short8 B2 = *reinterpret_cast<const short8*>(&pB[(size_t)c*32 + 16 + 4*g]);
    float pcol = 1.0f;
    #pragma unroll
    for (int mt = 0; mt < 4; ++mt) {
      f32x4 acc = {0.0f, 0.0f, 0.0f, 0.0f};
      acc = __builtin_amdgcn_mfma_f32_16x16x32_bf16(A1[mt], B1, acc, 0, 0, 0);
      acc = __builtin_amdgcn_mfma_f32_16x16x32_bf16(A2[mt], B2, acc, 0, 0, 0);
      pcol *= (1.0f + acc[0]) * (1.0f + acc[1]) * (1.0f + acc[2]) * (1.0f + acc[3]);
    }
    pcol *= __shfl_xor(pcol, 16, 64);
    pcol *= __shfl_xor(pcol, 32, 64);
    if (g == 0) ws_p[(size_t)chunk*HID + c] = pcol;
  }
}

// tailA: per-h product over all chunks, y0, per-block partial logits.
__global__ __launch_bounds__(256) void tailA_kernel(
    const float* __restrict__ ws_p, const float* __restrict__ Win,
    const float* __restrict__ bin,  const float* __restrict__ x0,
    const float* __restrict__ Wout, float* __restrict__ ws_lp) {
  const int b = blockIdx.x, tid = threadIdx.x;
  const int h0 = b * HPB;
  const int hh = tid & 15, sl = tid >> 4;

  __shared__ float sp[HPB][17];
  __shared__ float sy[HPB];

  {
    float p = 1.0f;
    #pragma unroll
    for (int i = 0; i < 16; ++i)
      p *= ws_p[(size_t)(sl*16 + i)*HID + h0 + hh];
    sp[hh][sl] = p;
  }
  __syncthreads();

  if (tid < HPB) {
    float P = 1.0f;
    #pragma unroll
    for (int s = 0; s < 16; ++s) P *= sp[tid][s];
    const int h = h0 + tid;
    const float4* __restrict__ wrow = reinterpret_cast<const float4*>(Win + (size_t)h*16);
    float y = bin[h];
    #pragma unroll
    for (int q = 0; q < 4; ++q) {
      float4 w = wrow[q];
      y = fmaf(w.x, x0[q*4+0], y);
      y = fmaf(w.y, x0[q*4+1], y);
      y = fmaf(w.z, x0[q*4+2], y);
      y = fmaf(w.w, x0[q*4+3], y);
    }
    sy[tid] = y * P;
  }
  __syncthreads();

  if (tid < NLAB*HPB) {                     // 160 threads
    const int j = tid >> 4, k = tid & 15;
    float v = Wout[(size_t)j*HID + h0 + k] * sy[k];
    v += __shfl_xor(v, 1, 64);
    v += __shfl_xor(v, 2, 64);
    v += __shfl_xor(v, 4, 64);
    v += __shfl_xor(v, 8, 64);
    if (k == 0) ws_lp[b*16 + j] = v;
  }
}

// tailB: one block sums 256x10 partial logits (deterministic order) + softmax
__global__ __launch_bounds__(256) void tailB_kernel(
    const float* __restrict__ ws_lp, const float* __restrict__ bout,
    float* __restrict__ out) {
  const int tid = threadIdx.x;
  __shared__ float slog[NLAB];

  if (tid < NLAB*16) {                      // j x 16 block-slices
    const int j = tid >> 4, s = tid & 15;
    float acc = 0.0f;
    #pragma unroll
    for (int bb = 0; bb < 16; ++bb)
      acc += ws_lp[(s*16 + bb)*16 + j];
    acc += __shfl_xor(acc, 1, 64);
    acc += __shfl_xor(acc, 2, 64);
    acc += __shfl_xor(acc, 4, 64);
    acc += __shfl_xor(acc, 8, 64);
    if (s == 0) slog[j] = acc + bout[j];
  }
  __syncthreads();
  if (tid == 0) {
    float m = slog[0];
    #pragma unroll
    for (int j = 1; j < NLAB; ++j) m = fmaxf(m, slog[j]);
    float ssum = 0.0f;
    float e[NLAB];
    #pragma unroll
    for (int j = 0; j < NLAB; ++j) { e[j] = __expf(slog[j] - m); ssum += e[j]; }
    const float inv = 1.0f / ssum;
    #pragma unroll
    for (int j = 0; j < NLAB; ++j) out[j] = e[j] * inv;
  }
}

extern "C" void kernel_launch(void* const* d_in, const int* in_sizes, int n_in,
                              void* d_out, int out_size, void* d_ws, size_t ws_size,
                              hipStream_t stream) {
  // inputs: 0=ts (unused), 1=logsigs (L,C), 2=x0 (D), 3=W_in (H,D), 4=b_in (H),
  //         5=vf_A (C,H), 6=W_out (10,H), 7=b_out (10)
  const float* logsigs = (const float*)d_in[1];
  const float* x0      = (const float*)d_in[2];
  const float* Win     = (const float*)d_in[3];
  const float* bin     = (const float*)d_in[4];
  const float* vfA     = (const float*)d_in[5];
  const float* Wout    = (const float*)d_in[6];
  const float* bout    = (const float*)d_in[7];
  float* out = (float*)d_out;

  // workspace layout (16B-aligned slices)
  float*    ws_p  = (float*)d_ws;                            // 256*4096 f32 = 4MB
  uint32_t* pB    = (uint32_t*)(ws_p + (size_t)NCHUNK*HID);  // 4096*32 u32 = 512KB
  float*    ws_lp = (float*)(pB + (size_t)HID*32);           // RBLK*16 f32

  pack_vfA_kernel<<<HID/256, 256, 0, stream>>>(vfA, pB);
  partial_mfma_kernel<<<dim3(4, NCHUNK), 256, 0, stream>>>(logsigs, pB, ws_p);
  tailA_kernel<<<RBLK, 256, 0, stream>>>(ws_p, Win, bin, x0, Wout, ws_lp);
  tailB_kernel<<<1, 256, 0, stream>>>(ws_lp, bout, out);
}